// Round 6
// baseline (842.386 us; speedup 1.0000x reference)
//
#include <hip/hip_runtime.h>
#include <cstdint>
#include <cstddef>

// ---------------------------------------------------------------------------
// MultiStageDiT round 6: attention occupancy fix (unified VGPR+AGPR budget):
// rel-pos tables hoisted to tab_k (full occupancy), attn_k slimmed to ~140
// total regs + launch_bounds(256,3); K/V double-buffered (1 barrier/kt,
// issue-early/write-late V); Vt write-conflict-free swizzle.
// GEMM / LN / prep kernels unchanged.
// ---------------------------------------------------------------------------

typedef float  f32x4    __attribute__((ext_vector_type(4)));
typedef __bf16 bf16x8_t __attribute__((ext_vector_type(8)));
typedef __bf16 bf16x4_t __attribute__((ext_vector_type(4)));

#define DEV __device__ __forceinline__

DEV void gload_lds16(const void* g, void* l) {
    auto gp = (const uint32_t __attribute__((address_space(1)))*)(uintptr_t)g;
    auto lp = (uint32_t __attribute__((address_space(3)))*)(uint32_t)(uintptr_t)l;
    __builtin_amdgcn_global_load_lds(gp, lp, 16, 0, 0);
}

// 64-elem-row tile, 16B chunks XOR-swizzled by (row&7)
DEV bf16x8_t lds_frag(const __bf16* base, int row, int chunk, int row_elems) {
    return *(const bf16x8_t*)(base + row * row_elems + ((chunk ^ (row & 7)) << 3));
}

// 32-elem-row P tile: XOR key (row>>1)&3
DEV bf16x8_t p_frag(const __bf16* base, int row, int chunk) {
    return *(const bf16x8_t*)(base + row * 32 + ((chunk ^ ((row >> 1) & 3)) << 3));
}

// V^T tile elem address: key (d&7)^((d>>3)&7) -> write conflict-free,
// read <=2-way (free). Rows 128B, 16B-aligned chunks.
DEV int vt_addr(int d, int k) {
    return d * 64 + ((((k >> 3) ^ (d & 7) ^ ((d >> 3) & 7)) << 3) | (k & 7));
}

DEV float gelu_tanh(float v) {
    float u = 0.7978845608028654f * (v + 0.044715f * v * v * v);
    float e = __expf(2.f * u);
    float th = 1.f - 2.f / (e + 1.f);
    return 0.5f * v * (1.f + th);
}

DEV int win2tok(int r) {
    int nb = r >> 12, wi = (r >> 8) & 15, l = r & 255;
    return (nb << 12) + (wi >> 2) * 1024 + (l >> 4) * 64 + (wi & 3) * 16 + (l & 15);
}

// ---------------------------------------------------------------------------
// prep kernels (unchanged)
// ---------------------------------------------------------------------------
__global__ void silu_k(const float* __restrict__ c, float* __restrict__ o, int n) {
    int i = blockIdx.x * 256 + threadIdx.x;
    if (i < n) { float v = c[i]; o[i] = v / (1.f + __expf(-v)); }
}

__global__ void zero_k(float* o, int n) {
    int i = blockIdx.x * 256 + threadIdx.x;
    if (i < n) o[i] = 0.f;
}

__global__ void conv_bf16(const float* __restrict__ s, __bf16* __restrict__ d, int n4) {
    int i = blockIdx.x * 256 + threadIdx.x;
    if (i < n4) {
        float4 v = ((const float4*)s)[i];
        bf16x4_t o; o[0] = (__bf16)v.x; o[1] = (__bf16)v.y; o[2] = (__bf16)v.z; o[3] = (__bf16)v.w;
        ((bf16x4_t*)d)[i] = o;
    }
}

__global__ __launch_bounds__(256)
void mod_gemv(const float* __restrict__ sc, const float* __restrict__ w,
              const float* __restrict__ b, float* __restrict__ mod) {
    int o = (blockIdx.x << 2) + (threadIdx.x >> 6);
    int lane = threadIdx.x & 63;
    int n = o / 6144, col = o % 6144;
    const float4* wr = (const float4*)(w + (size_t)col * 1024);
    const float4* sr = (const float4*)(sc + n * 1024);
    float acc = 0.f;
    #pragma unroll 4
    for (int i = lane; i < 256; i += 64) {
        float4 a = wr[i], x = sr[i];
        acc += a.x * x.x + a.y * x.y + a.z * x.z + a.w * x.w;
    }
    #pragma unroll
    for (int m = 1; m < 64; m <<= 1) acc += __shfl_xor(acc, m);
    if (lane == 0) mod[o] = acc + b[col];
}

__global__ __launch_bounds__(256)
void ln_mod_k(const float* __restrict__ src, const float* __restrict__ mod,
              int sh_off, int sc_off, __bf16* __restrict__ out, int permute, int r0) {
    int rl = blockIdx.x;
    int r = rl + r0;
    int nb = r >> 12;
    int t = permute ? win2tok(r) : r;
    float4 v = ((const float4*)(src + (size_t)t * 1024))[threadIdx.x];
    float s  = v.x + v.y + v.z + v.w;
    float sq = v.x * v.x + v.y * v.y + v.z * v.z + v.w * v.w;
    #pragma unroll
    for (int m = 1; m < 64; m <<= 1) { s += __shfl_xor(s, m); sq += __shfl_xor(sq, m); }
    __shared__ float ps[4], pq[4];
    int wv = threadIdx.x >> 6, ln = threadIdx.x & 63;
    if (ln == 0) { ps[wv] = s; pq[wv] = sq; }
    __syncthreads();
    s  = ps[0] + ps[1] + ps[2] + ps[3];
    sq = pq[0] + pq[1] + pq[2] + pq[3];
    float mean = s * (1.f / 1024.f);
    float var  = sq * (1.f / 1024.f) - mean * mean;
    float rstd = rsqrtf(var + 1e-6f);
    int c = threadIdx.x << 2;
    const float* mrow = mod + nb * 6144;
    float4 scv = *(const float4*)(mrow + sc_off + c);
    float4 shv = *(const float4*)(mrow + sh_off + c);
    bf16x4_t o;
    o[0] = (__bf16)((v.x - mean) * rstd * (1.f + scv.x) + shv.x);
    o[1] = (__bf16)((v.y - mean) * rstd * (1.f + scv.y) + shv.y);
    o[2] = (__bf16)((v.z - mean) * rstd * (1.f + scv.z) + shv.z);
    o[3] = (__bf16)((v.w - mean) * rstd * (1.f + scv.w) + shv.w);
    *(bf16x4_t*)(out + (size_t)rl * 1024 + c) = o;
}

// ---------------------------------------------------------------------------
// bf16 GEMM (unchanged — 2-phase dbuf, global_load_lds)
// ---------------------------------------------------------------------------
template <int EPI>
__global__ __launch_bounds__(256)
void gemm_bt(const __bf16* __restrict__ A, const __bf16* __restrict__ B,
             const float* __restrict__ bias, void* __restrict__ Cout,
             const float* __restrict__ extra, const float* __restrict__ mod,
             int N, int K, int r0) {
    __shared__ __align__(16) __bf16 lA[2][128 * 64];
    __shared__ __align__(16) __bf16 lB[2][128 * 64];
    const int tid = threadIdx.x, lane = tid & 63, wv = tid >> 6;
    const int wr = wv >> 1, wc = wv & 1;
    const int bm = blockIdx.y << 7, bn = blockIdx.x << 7;

    f32x4 acc[4][4];
    const f32x4 z4 = {0.f, 0.f, 0.f, 0.f};
    #pragma unroll
    for (int i = 0; i < 4; ++i)
        #pragma unroll
        for (int j = 0; j < 4; ++j) acc[i][j] = z4;

    const int srow = lane >> 3;
    const int gc   = (lane & 7) ^ srow;
    const size_t arow = (size_t)(bm + srow) * K + (gc << 3);
    const size_t brow = (size_t)(bn + srow) * K + (gc << 3);

    const int nt = K >> 6;
    int cur = 0;
    #pragma unroll
    for (int q = 0; q < 4; ++q) {
        int rr = (wv << 5) + (q << 3);
        gload_lds16(A + arow + (size_t)rr * K, &lA[0][rr * 64]);
        gload_lds16(B + brow + (size_t)rr * K, &lB[0][rr * 64]);
    }

    for (int t = 0; t < nt; ++t) {
        __syncthreads();
        if (t + 1 < nt) {
            const size_t k1 = (size_t)(t + 1) << 6;
            #pragma unroll
            for (int q = 0; q < 4; ++q) {
                int rr = (wv << 5) + (q << 3);
                gload_lds16(A + arow + (size_t)rr * K + k1, &lA[cur ^ 1][rr * 64]);
                gload_lds16(B + brow + (size_t)rr * K + k1, &lB[cur ^ 1][rr * 64]);
            }
        }
        #pragma unroll
        for (int ks = 0; ks < 2; ++ks) {
            bf16x8_t af[4], bfr[4];
            #pragma unroll
            for (int i = 0; i < 4; ++i) {
                af[i]  = lds_frag(lA[cur], (wr << 6) + (i << 4) + (lane & 15), (ks << 2) + (lane >> 4), 64);
                bfr[i] = lds_frag(lB[cur], (wc << 6) + (i << 4) + (lane & 15), (ks << 2) + (lane >> 4), 64);
            }
            #pragma unroll
            for (int mi = 0; mi < 4; ++mi)
                #pragma unroll
                for (int ni = 0; ni < 4; ++ni)
                    acc[mi][ni] = __builtin_amdgcn_mfma_f32_16x16x32_bf16(af[mi], bfr[ni], acc[mi][ni], 0, 0, 0);
        }
        cur ^= 1;
    }

    #pragma unroll
    for (int mi = 0; mi < 4; ++mi) {
        #pragma unroll
        for (int j = 0; j < 4; ++j) {
            int m = bm + (wr << 6) + (mi << 4) + ((lane >> 4) << 2) + j;
            #pragma unroll
            for (int ni = 0; ni < 4; ++ni) {
                int n = bn + (wc << 6) + (ni << 4) + (lane & 15);
                float v = acc[mi][ni][j] + bias[n];
                if constexpr (EPI == 0) {
                    ((__bf16*)Cout)[(size_t)m * N + n] = (__bf16)v;
                } else if constexpr (EPI == 1) {
                    int mg = m + r0;
                    int tr = win2tok(mg);
                    float g = mod[(mg >> 12) * 6144 + 2048 + n];
                    ((float*)Cout)[(size_t)tr * 1024 + n] = extra[(size_t)tr * 1024 + n] + g * v;
                } else if constexpr (EPI == 2) {
                    ((__bf16*)Cout)[(size_t)m * N + n] = (__bf16)gelu_tanh(v);
                } else {
                    int mg = m + r0;
                    float g = mod[(mg >> 12) * 6144 + 5120 + n];
                    ((float*)Cout)[(size_t)mg * 1024 + n] = extra[(size_t)mg * 1024 + n] + g * v;
                }
            }
        }
    }
}

// ---------------------------------------------------------------------------
// Rel-pos bias tables: tab[((l>>8)*16 + h)*256 + (l&255)][32] bf16,
// [0..16) = Th(l,h,kk), [16..32) = Tw(l,h,kk). Block = 128 rows x 1 head,
// thread = (row, kk-half). Full-occupancy VALU kernel.
// ---------------------------------------------------------------------------
__global__ __launch_bounds__(256)
void tab_k(const __bf16* __restrict__ qkv, const float* __restrict__ relh,
           const float* __restrict__ relw, __bf16* __restrict__ tab) {
    const int h = blockIdx.y;
    const int r = threadIdx.x >> 1, half = threadIdx.x & 1;
    const int l = blockIdx.x * 128 + r;          // chunk-local window row
    const int lw = l & 255;
    const int qi = lw >> 4, qj = lw & 15;
    const __bf16* qrow = qkv + (size_t)l * 3072 + h * 64;
    float qq[64];
    #pragma unroll
    for (int c8 = 0; c8 < 8; ++c8) {
        bf16x8_t q8 = *(const bf16x8_t*)(qrow + (c8 << 3));
        #pragma unroll
        for (int e = 0; e < 8; ++e) qq[c8 * 8 + e] = (float)q8[e];
    }
    bf16x8_t oh, ow;
    #pragma unroll
    for (int kk = 0; kk < 8; ++kk) {
        int kg = (half << 3) + kk;
        const float4* rh = (const float4*)(relh + (size_t)(qi - kg + 15) * 64);
        const float4* rw = (const float4*)(relw + (size_t)(qj - kg + 15) * 64);
        float ah = 0.f, aw = 0.f;
        #pragma unroll
        for (int c4 = 0; c4 < 16; ++c4) {
            float4 r1 = rh[c4], r2 = rw[c4];
            ah += qq[c4*4]*r1.x + qq[c4*4+1]*r1.y + qq[c4*4+2]*r1.z + qq[c4*4+3]*r1.w;
            aw += qq[c4*4]*r2.x + qq[c4*4+1]*r2.y + qq[c4*4+2]*r2.z + qq[c4*4+3]*r2.w;
        }
        oh[kk] = (__bf16)ah; ow[kk] = (__bf16)aw;
    }
    size_t idx = ((size_t)(l >> 8) * 16 + h) * 256 + lw;
    *(bf16x8_t*)(tab + idx * 32 + (half << 3))      = oh;
    *(bf16x8_t*)(tab + idx * 32 + 16 + (half << 3)) = ow;
}

// ---------------------------------------------------------------------------
// Window attention v3. Block = (window, head, q-half); 4 waves x 32 q-rows.
// Tables from tab (LDS-staged). K via global_load_lds (swizzled source),
// V reg-staged transposed (conflict-free key). K/V double-buffered,
// ONE barrier per k-tile; V writes issue-early/write-late (T14).
// Non-online softmax (bounded scores). launch_bounds(256,3): total reg
// budget ~170 incl. AGPRs (round-5 lesson: unified file, 160+acc > 256
// silently dropped occupancy to 1 wave/SIMD).
// ---------------------------------------------------------------------------
__global__ __launch_bounds__(256, 3)
void attn_k(const __bf16* __restrict__ qkv, const __bf16* __restrict__ tab,
            __bf16* __restrict__ out) {
    __shared__ __align__(16) __bf16 lP[4][32 * 32];     // 8KB (per-wave P half)
    __shared__ __align__(16) __bf16 lKt[2][64 * 64];    // 16KB
    __shared__ __align__(16) __bf16 lVt[2][64 * 64];    // 16KB
    __shared__ __align__(16) __bf16 lTab[128 * 32];     // 8KB

    const int blk = blockIdx.x;
    const int winc = blk >> 5, h = (blk >> 1) & 15, qh = blk & 1;
    const int tid = threadIdx.x, lane = tid & 63, wv = tid >> 6;
    const __bf16* base = qkv + (size_t)winc * 256 * 3072 + h * 64;
    const int q0 = qh << 7;

    // ---- stage table slice (8KB, linear copy) ----
    {
        const __bf16* ts = tab + (((size_t)winc * 16 + h) * 256 + q0) * 32;
        #pragma unroll
        for (int q = 0; q < 2; ++q) {
            int c = (wv << 1) + q;
            gload_lds16(ts + c * 512 + lane * 8, lTab + c * 512);
        }
    }
    // ---- Q fragments (32 q-rows per wave) ----
    bf16x8_t qf[2][2];
    #pragma unroll
    for (int mi = 0; mi < 2; ++mi)
        #pragma unroll
        for (int ks = 0; ks < 2; ++ks) {
            int l = q0 + (wv << 5) + (mi << 4) + (lane & 15);
            qf[mi][ks] = *(const bf16x8_t*)(base + (size_t)l * 3072 + (((ks << 2) + (lane >> 4)) << 3));
        }
    // ---- prologue: stage kt=0 ----
    {
        const __bf16* kb = base + 1024;
        #pragma unroll
        for (int q = 0; q < 2; ++q) {
            int c = (wv << 1) + q;
            int kl = (c << 3) + (lane >> 3);
            gload_lds16(kb + (size_t)kl * 3072 + (((lane & 7) ^ (lane >> 3)) << 3),
                        lKt[0] + c * 512);
        }
        const __bf16* vb = base + 2048;
        bf16x8_t a = *(const bf16x8_t*)(vb + (size_t)(tid >> 3) * 3072 + ((tid & 7) << 3));
        bf16x8_t b = *(const bf16x8_t*)(vb + (size_t)(32 + (tid >> 3)) * 3072 + ((tid & 7) << 3));
        int lc = tid & 7;
        #pragma unroll
        for (int e = 0; e < 8; ++e) {
            lVt[0][vt_addr(lc * 8 + e, tid >> 3)]      = a[e];
            lVt[0][vt_addr(lc * 8 + e, 32 + (tid >> 3))] = b[e];
        }
    }
    __syncthreads();

    // ---- hoisted Tw (kj = lane&15, invariant over kt) ----
    float twv[2][4];
    #pragma unroll
    for (int mi = 0; mi < 2; ++mi)
        #pragma unroll
        for (int j = 0; j < 4; ++j) {
            int qr = (wv << 5) + (mi << 4) + ((lane >> 4) << 2) + j;
            twv[mi][j] = (float)lTab[qr * 32 + 16 + (lane & 15)];
        }

    const f32x4 z4 = {0.f, 0.f, 0.f, 0.f};
    f32x4 oacc[2][4];
    #pragma unroll
    for (int a = 0; a < 2; ++a)
        #pragma unroll
        for (int b = 0; b < 4; ++b) oacc[a][b] = z4;
    float rsum[2][4];
    #pragma unroll
    for (int a = 0; a < 2; ++a)
        #pragma unroll
        for (int j = 0; j < 4; ++j) rsum[a][j] = 0.f;
    __bf16* lPw = lP[wv];

    int cur = 0;
    for (int kt = 0; kt < 4; ++kt) {
        const bool pre = (kt < 3);
        bf16x8_t v8a, v8b;
        if (pre) {                       // issue next tile's loads EARLY
            const __bf16* kb = base + 1024 + (size_t)(kt + 1) * 64 * 3072;
            #pragma unroll
            for (int q = 0; q < 2; ++q) {
                int c = (wv << 1) + q;
                int kl = (c << 3) + (lane >> 3);
                gload_lds16(kb + (size_t)kl * 3072 + (((lane & 7) ^ (lane >> 3)) << 3),
                            lKt[cur ^ 1] + c * 512);
            }
            const __bf16* vb = base + 2048 + (size_t)(kt + 1) * 64 * 3072;
            v8a = *(const bf16x8_t*)(vb + (size_t)(tid >> 3) * 3072 + ((tid & 7) << 3));
            v8b = *(const bf16x8_t*)(vb + (size_t)(32 + (tid >> 3)) * 3072 + ((tid & 7) << 3));
        }

        // ---- QK^T ----
        f32x4 s[2][4];
        #pragma unroll
        for (int a = 0; a < 2; ++a)
            #pragma unroll
            for (int b = 0; b < 4; ++b) s[a][b] = z4;
        #pragma unroll
        for (int ks = 0; ks < 2; ++ks) {
            bf16x8_t kf[4];
            #pragma unroll
            for (int ni = 0; ni < 4; ++ni)
                kf[ni] = lds_frag(lKt[cur], (ni << 4) + (lane & 15), (ks << 2) + (lane >> 4), 64);
            #pragma unroll
            for (int mi = 0; mi < 2; ++mi)
                #pragma unroll
                for (int ni = 0; ni < 4; ++ni)
                    s[mi][ni] = __builtin_amdgcn_mfma_f32_16x16x32_bf16(qf[mi][ks], kf[ni], s[mi][ni], 0, 0, 0);
        }

        // ---- bias + exp + partial rowsums ----
        #pragma unroll
        for (int mi = 0; mi < 2; ++mi) {
            #pragma unroll
            for (int j = 0; j < 4; ++j) {
                int qr = (wv << 5) + (mi << 4) + ((lane >> 4) << 2) + j;
                bf16x4_t th4 = *(const bf16x4_t*)(lTab + qr * 32 + (kt << 2));
                float rs = 0.f;
                #pragma unroll
                for (int ni = 0; ni < 4; ++ni) {
                    float p = __expf(s[mi][ni][j] * 0.125f + (float)th4[ni] + twv[mi][j]);
                    s[mi][ni][j] = p;
                    rs += p;
                }
                rsum[mi][j] += rs;
            }
        }

        // ---- per 32-k half: P write (wave-private) + PV ----
        #pragma unroll
        for (int hf = 0; hf < 2; ++hf) {
            #pragma unroll
            for (int mi = 0; mi < 2; ++mi) {
                #pragma unroll
                for (int j = 0; j < 4; ++j) {
                    int rl = (mi << 4) + ((lane >> 4) << 2) + j;
                    #pragma unroll
                    for (int b = 0; b < 2; ++b) {
                        int col = (b << 4) + (lane & 15);
                        lPw[rl * 32 + ((((col >> 3) ^ ((rl >> 1) & 3)) << 3) | (col & 7))] =
                            (__bf16)s[mi][(hf << 1) + b][j];
                    }
                }
            }
            bf16x8_t pf[2], vf[4];
            #pragma unroll
            for (int mi = 0; mi < 2; ++mi)
                pf[mi] = p_frag(lPw, (mi << 4) + (lane & 15), lane >> 4);
            #pragma unroll
            for (int no = 0; no < 4; ++no) {
                int d = (no << 4) + (lane & 15);
                vf[no] = *(const bf16x8_t*)(lVt[cur] + vt_addr(d, ((hf << 2) + (lane >> 4)) << 3));
            }
            #pragma unroll
            for (int mi = 0; mi < 2; ++mi)
                #pragma unroll
                for (int no = 0; no < 4; ++no)
                    oacc[mi][no] = __builtin_amdgcn_mfma_f32_16x16x32_bf16(pf[mi], vf[no], oacc[mi][no], 0, 0, 0);
        }

        if (pre) {                       // write-LATE: V -> LDS (buf^1)
            int lc = tid & 7;
            #pragma unroll
            for (int e = 0; e < 8; ++e) {
                lVt[cur ^ 1][vt_addr(lc * 8 + e, tid >> 3)]        = v8a[e];
                lVt[cur ^ 1][vt_addr(lc * 8 + e, 32 + (tid >> 3))] = v8b[e];
            }
        }
        __syncthreads();                 // drains gload (vmcnt) + ds writes
        cur ^= 1;
    }

    // ---- final row-sum reduction + normalize + store ----
    #pragma unroll
    for (int mi = 0; mi < 2; ++mi) {
        #pragma unroll
        for (int j = 0; j < 4; ++j) {
            float rs = rsum[mi][j];
            #pragma unroll
            for (int msk = 1; msk < 16; msk <<= 1) rs += __shfl_xor(rs, msk);
            float inv = 1.f / rs;
            int l = q0 + (wv << 5) + (mi << 4) + ((lane >> 4) << 2) + j;
            #pragma unroll
            for (int no = 0; no < 4; ++no) {
                int col = (no << 4) + (lane & 15);
                out[(size_t)(winc * 256 + l) * 1024 + h * 64 + col] = (__bf16)(oacc[mi][no][j] * inv);
            }
        }
    }
}

// ---------------------------------------------------------------------------
extern "C" void kernel_launch(void* const* d_in, const int* in_sizes, int n_in,
                              void* d_out, int out_size, void* d_ws, size_t ws_size,
                              hipStream_t stream) {
    const float* x      = (const float*)d_in[0];
    const float* c      = (const float*)d_in[1];
    const float* qkv_w  = (const float*)d_in[2];
    const float* qkv_b  = (const float*)d_in[3];
    const float* proj_w = (const float*)d_in[4];
    const float* proj_b = (const float*)d_in[5];
    const float* rel_h  = (const float*)d_in[6];
    const float* rel_w  = (const float*)d_in[7];
    const float* ada_w  = (const float*)d_in[8];
    const float* ada_b  = (const float*)d_in[9];
    const float* fc1_w  = (const float*)d_in[10];
    const float* fc1_b  = (const float*)d_in[11];
    const float* fc2_w  = (const float*)d_in[12];
    const float* fc2_b  = (const float*)d_in[13];
    float* xo = (float*)d_out;

    char* ws = (char*)d_ws;
    const size_t MB = 1ull << 20;
    int CH = 0;
    const int cands[7] = {16384, 8192, 4096, 2048, 1024, 512, 256};
    for (int i = 0; i < 7; ++i)
        if (26 * MB + (size_t)cands[i] * 10240 <= ws_size) { CH = cands[i]; break; }
    if (CH == 0) {
        zero_k<<<65536, 256, 0, stream>>>(xo, 16777216);
        return;
    }
    const int NCH = 16384 / CH;

    float*  ws_silu = (float*)(ws);
    float*  ws_mod  = (float*)(ws + 65536);
    __bf16* w_qkv   = (__bf16*)(ws + 1 * MB);
    __bf16* w_proj  = (__bf16*)(ws + 7 * MB);
    __bf16* w_fc1   = (__bf16*)(ws + 9 * MB);
    __bf16* w_fc2   = (__bf16*)(ws + 17 * MB);
    __bf16* bufA    = (__bf16*)(ws + 26 * MB);
    __bf16* bufB    = (__bf16*)(ws + 26 * MB + (size_t)CH * 2048);
    // qkv occupies CH*6KB of bufB's CH*8KB rows budget; table lives in the tail
    __bf16* tabbuf  = bufB + (size_t)CH * 3072;      // CH*1KB (fits CH*2KB tail)

    silu_k   <<<16,   256, 0, stream>>>(c, ws_silu, 4096);
    mod_gemv <<<6144, 256, 0, stream>>>(ws_silu, ada_w, ada_b, ws_mod);
    conv_bf16<<<3072, 256, 0, stream>>>(qkv_w,  w_qkv,  786432);
    conv_bf16<<<1024, 256, 0, stream>>>(proj_w, w_proj, 262144);
    conv_bf16<<<4096, 256, 0, stream>>>(fc1_w,  w_fc1,  1048576);
    conv_bf16<<<4096, 256, 0, stream>>>(fc2_w,  w_fc2,  1048576);

    for (int ci = 0; ci < NCH; ++ci) {
        int r0 = ci * CH;
        ln_mod_k<<<CH, 256, 0, stream>>>(x, ws_mod, 0, 1024, bufA, 1, r0);
        gemm_bt<0><<<dim3(24, CH / 128), 256, 0, stream>>>(bufA, w_qkv, qkv_b, bufB,
                                                           nullptr, nullptr, 3072, 1024, r0);
        tab_k<<<dim3(CH / 128, 16), 256, 0, stream>>>(bufB, rel_h, rel_w, tabbuf);
        attn_k<<<(CH / 256) * 32, 256, 0, stream>>>(bufB, tabbuf, bufA);
        gemm_bt<1><<<dim3(8, CH / 128), 256, 0, stream>>>(bufA, w_proj, proj_b, xo,
                                                          x, ws_mod, 1024, 1024, r0);
    }
    for (int ci = 0; ci < NCH; ++ci) {
        int r0 = ci * CH;
        ln_mod_k<<<CH, 256, 0, stream>>>(xo, ws_mod, 3072, 4096, bufA, 0, r0);
        gemm_bt<2><<<dim3(32, CH / 128), 256, 0, stream>>>(bufA, w_fc1, fc1_b, bufB,
                                                           nullptr, nullptr, 4096, 1024, r0);
        gemm_bt<3><<<dim3(8, CH / 128), 256, 0, stream>>>(bufB, w_fc2, fc2_b, xo,
                                                          xo, ws_mod, 1024, 4096, r0);
    }
}

// Round 7
// 644.552 us; speedup vs baseline: 1.3069x; 1.3069x over previous
//
#include <hip/hip_runtime.h>
#include <cstdint>
#include <cstddef>

// ---------------------------------------------------------------------------
// MultiStageDiT round 7: (1) tab_k rebuilt with LDS-staged bf16 rel tables
// (kills 256 scattered L1 gathers/thread); (2) GEMMs ported to 256x256
// 8-phase schedule: 8 waves, BK=64, counted vmcnt(6) (never 0 in loop),
// raw s_barrier (NOT __syncthreads), T2 XOR swizzle, setprio MFMA clusters.
// attn_k / LN / prep unchanged from round 6 (passing).
// ---------------------------------------------------------------------------

typedef float  f32x4    __attribute__((ext_vector_type(4)));
typedef __bf16 bf16x8_t __attribute__((ext_vector_type(8)));
typedef __bf16 bf16x4_t __attribute__((ext_vector_type(4)));

#define DEV __device__ __forceinline__

DEV void gload_lds16(const void* g, void* l) {
    auto gp = (const uint32_t __attribute__((address_space(1)))*)(uintptr_t)g;
    auto lp = (uint32_t __attribute__((address_space(3)))*)(uint32_t)(uintptr_t)l;
    __builtin_amdgcn_global_load_lds(gp, lp, 16, 0, 0);
}

// row-major LDS tile, 16B chunks XOR-swizzled by (row&7)
DEV bf16x8_t lds_frag(const __bf16* base, int row, int chunk, int row_elems) {
    return *(const bf16x8_t*)(base + row * row_elems + ((chunk ^ (row & 7)) << 3));
}

// 32-elem-row P tile: XOR key (row>>1)&3
DEV bf16x8_t p_frag(const __bf16* base, int row, int chunk) {
    return *(const bf16x8_t*)(base + row * 32 + ((chunk ^ ((row >> 1) & 3)) << 3));
}

// V^T tile elem address: key (d&7)^((d>>3)&7)
DEV int vt_addr(int d, int k) {
    return d * 64 + ((((k >> 3) ^ (d & 7) ^ ((d >> 3) & 7)) << 3) | (k & 7));
}

DEV float gelu_tanh(float v) {
    float u = 0.7978845608028654f * (v + 0.044715f * v * v * v);
    float e = __expf(2.f * u);
    float th = 1.f - 2.f / (e + 1.f);
    return 0.5f * v * (1.f + th);
}

DEV int win2tok(int r) {
    int nb = r >> 12, wi = (r >> 8) & 15, l = r & 255;
    return (nb << 12) + (wi >> 2) * 1024 + (l >> 4) * 64 + (wi & 3) * 16 + (l & 15);
}

// ---------------------------------------------------------------------------
// prep kernels
// ---------------------------------------------------------------------------
__global__ void silu_k(const float* __restrict__ c, float* __restrict__ o, int n) {
    int i = blockIdx.x * 256 + threadIdx.x;
    if (i < n) { float v = c[i]; o[i] = v / (1.f + __expf(-v)); }
}

__global__ void zero_k(float* o, int n) {
    int i = blockIdx.x * 256 + threadIdx.x;
    if (i < n) o[i] = 0.f;
}

__global__ void conv_bf16(const float* __restrict__ s, __bf16* __restrict__ d, int n4) {
    int i = blockIdx.x * 256 + threadIdx.x;
    if (i < n4) {
        float4 v = ((const float4*)s)[i];
        bf16x4_t o; o[0] = (__bf16)v.x; o[1] = (__bf16)v.y; o[2] = (__bf16)v.z; o[3] = (__bf16)v.w;
        ((bf16x4_t*)d)[i] = o;
    }
}

__global__ __launch_bounds__(256)
void mod_gemv(const float* __restrict__ sc, const float* __restrict__ w,
              const float* __restrict__ b, float* __restrict__ mod) {
    int o = (blockIdx.x << 2) + (threadIdx.x >> 6);
    int lane = threadIdx.x & 63;
    int n = o / 6144, col = o % 6144;
    const float4* wr = (const float4*)(w + (size_t)col * 1024);
    const float4* sr = (const float4*)(sc + n * 1024);
    float acc = 0.f;
    #pragma unroll 4
    for (int i = lane; i < 256; i += 64) {
        float4 a = wr[i], x = sr[i];
        acc += a.x * x.x + a.y * x.y + a.z * x.z + a.w * x.w;
    }
    #pragma unroll
    for (int m = 1; m < 64; m <<= 1) acc += __shfl_xor(acc, m);
    if (lane == 0) mod[o] = acc + b[col];
}

__global__ __launch_bounds__(256)
void ln_mod_k(const float* __restrict__ src, const float* __restrict__ mod,
              int sh_off, int sc_off, __bf16* __restrict__ out, int permute, int r0) {
    int rl = blockIdx.x;
    int r = rl + r0;
    int nb = r >> 12;
    int t = permute ? win2tok(r) : r;
    float4 v = ((const float4*)(src + (size_t)t * 1024))[threadIdx.x];
    float s  = v.x + v.y + v.z + v.w;
    float sq = v.x * v.x + v.y * v.y + v.z * v.z + v.w * v.w;
    #pragma unroll
    for (int m = 1; m < 64; m <<= 1) { s += __shfl_xor(s, m); sq += __shfl_xor(sq, m); }
    __shared__ float ps[4], pq[4];
    int wv = threadIdx.x >> 6, ln = threadIdx.x & 63;
    if (ln == 0) { ps[wv] = s; pq[wv] = sq; }
    __syncthreads();
    s  = ps[0] + ps[1] + ps[2] + ps[3];
    sq = pq[0] + pq[1] + pq[2] + pq[3];
    float mean = s * (1.f / 1024.f);
    float var  = sq * (1.f / 1024.f) - mean * mean;
    float rstd = rsqrtf(var + 1e-6f);
    int c = threadIdx.x << 2;
    const float* mrow = mod + nb * 6144;
    float4 scv = *(const float4*)(mrow + sc_off + c);
    float4 shv = *(const float4*)(mrow + sh_off + c);
    bf16x4_t o;
    o[0] = (__bf16)((v.x - mean) * rstd * (1.f + scv.x) + shv.x);
    o[1] = (__bf16)((v.y - mean) * rstd * (1.f + scv.y) + shv.y);
    o[2] = (__bf16)((v.z - mean) * rstd * (1.f + scv.z) + shv.z);
    o[3] = (__bf16)((v.w - mean) * rstd * (1.f + scv.w) + shv.w);
    *(bf16x4_t*)(out + (size_t)rl * 1024 + c) = o;
}

// ---------------------------------------------------------------------------
// 256x256 8-phase bf16 GEMM.  C[M,N] = A[M,K] @ B[N,K]^T + bias.
// 512 threads = 8 waves (2M x 4N); per-wave C = 128x64; acc[8][4] f32x4.
// BK=64. LDS 128KB dynamic (2 dbuf x (A 32KB + B 32KB)).
// Phases per K-tile: q00,q01,q10,q11; stage order for t+1: Atop,Btop,Bbot,Abot
// (one 16KB half per phase, 2 global_load_lds/thread). vmcnt(6) before each
// phase's ds_reads (tail: 4/2/0). Raw s_barrier only (NOT __syncthreads —
// that would drain vmcnt to 0 and kill the pipeline).
// Atop = A rows {0..63}u{128..191} (wave-row halves); Btop = B rows
// {0..31}u{64..95}u{128..159}u{192..223} (wave-col 32-row halves).
// ---------------------------------------------------------------------------
template <int PM, int PN>
DEV void mfma16(f32x4 (&acc)[8][4], bf16x8_t (&fa)[4][2], bf16x8_t (&fb)[2][2][2]) {
    #pragma unroll
    for (int ks = 0; ks < 2; ++ks)
        #pragma unroll
        for (int mi = 0; mi < 4; ++mi)
            #pragma unroll
            for (int nn = 0; nn < 2; ++nn)
                acc[PM * 4 + mi][PN * 2 + nn] = __builtin_amdgcn_mfma_f32_16x16x32_bf16(
                    fa[mi][ks], fb[PN][nn][ks], acc[PM * 4 + mi][PN * 2 + nn], 0, 0, 0);
}

template <int EPI>
__global__ __launch_bounds__(512)
void gemm256(const __bf16* __restrict__ A, const __bf16* __restrict__ B,
             const float* __restrict__ bias, void* __restrict__ Cout,
             const float* __restrict__ extra, const float* __restrict__ mod,
             int N, int K, int r0) {
    extern __shared__ __align__(16) char smem[];
    __bf16* lA = (__bf16*)smem;             // [2][256*64]
    __bf16* lB = lA + 2 * 256 * 64;         // [2][256*64]
    const int tid = threadIdx.x, lane = tid & 63, wv = tid >> 6;
    const int wr = wv >> 2, wc = wv & 3;
    const int bm = blockIdx.y << 8, bn = blockIdx.x << 8;

    f32x4 acc[8][4];
    const f32x4 z4 = {0.f, 0.f, 0.f, 0.f};
    #pragma unroll
    for (int i = 0; i < 8; ++i)
        #pragma unroll
        for (int j = 0; j < 4; ++j) acc[i][j] = z4;

    bf16x8_t fa[4][2], fb[2][2][2];
    const int gc8 = (((lane & 7) ^ (lane >> 3)) << 3);   // pre-swizzled src chunk

    auto stageA = [&](int buf, int k0, int h) {
        #pragma unroll
        for (int j = 0; j < 2; ++j) {
            int rb = (h << 6) + (j << 7) + (wv << 3);           // wave-uniform
            gload_lds16(A + (size_t)(bm + rb + (lane >> 3)) * K + k0 + gc8,
                        lA + buf * 16384 + rb * 64);
        }
    };
    auto stageB = [&](int buf, int k0, int h) {
        #pragma unroll
        for (int j = 0; j < 2; ++j) {
            int rb = (h << 5) + (j << 7) + ((wv & 3) << 3) + ((wv >> 2) << 6);
            gload_lds16(B + (size_t)(bn + rb + (lane >> 3)) * K + k0 + gc8,
                        lB + buf * 16384 + rb * 64);
        }
    };
    auto readA = [&](int buf, int pm) {
        #pragma unroll
        for (int mi = 0; mi < 4; ++mi)
            #pragma unroll
            for (int ks = 0; ks < 2; ++ks)
                fa[mi][ks] = lds_frag(lA + buf * 16384,
                                      (wr << 7) + (pm << 6) + (mi << 4) + (lane & 15),
                                      (ks << 2) + (lane >> 4), 64);
    };
    auto readB = [&](int buf, int pn) {
        #pragma unroll
        for (int ni = 0; ni < 2; ++ni)
            #pragma unroll
            for (int ks = 0; ks < 2; ++ks)
                fb[pn][ni][ks] = lds_frag(lB + buf * 16384,
                                          (wc << 6) + (pn << 5) + (ni << 4) + (lane & 15),
                                          (ks << 2) + (lane >> 4), 64);
    };

    const int nt = K >> 6;
    // prologue: stage tile 0 (order Atop, Btop, Bbot, Abot)
    stageA(0, 0, 0); stageB(0, 0, 0); stageB(0, 0, 1); stageA(0, 0, 1);

    int cur = 0;
    for (int t = 0; t < nt - 1; ++t) {
        const int nk0 = (t + 1) << 6;
        // ---- phase 0 (q00): stage A'top; need cur Atop+Btop ----
        stageA(cur ^ 1, nk0, 0);
        asm volatile("s_waitcnt vmcnt(6)" ::: "memory");
        __builtin_amdgcn_s_barrier();
        __builtin_amdgcn_sched_barrier(0);
        readA(cur, 0); readB(cur, 0);
        asm volatile("s_waitcnt lgkmcnt(0)" ::: "memory");
        __builtin_amdgcn_sched_barrier(0);
        __builtin_amdgcn_s_setprio(1); mfma16<0, 0>(acc, fa, fb); __builtin_amdgcn_s_setprio(0);
        // ---- phase 1 (q01): stage B'top; need cur Bbot ----
        stageB(cur ^ 1, nk0, 0);
        asm volatile("s_waitcnt vmcnt(6)" ::: "memory");
        __builtin_amdgcn_s_barrier();
        __builtin_amdgcn_sched_barrier(0);
        readB(cur, 1);
        asm volatile("s_waitcnt lgkmcnt(0)" ::: "memory");
        __builtin_amdgcn_sched_barrier(0);
        __builtin_amdgcn_s_setprio(1); mfma16<0, 1>(acc, fa, fb); __builtin_amdgcn_s_setprio(0);
        // ---- phase 2 (q10): stage B'bot; need cur Abot ----
        stageB(cur ^ 1, nk0, 1);
        asm volatile("s_waitcnt vmcnt(6)" ::: "memory");
        __builtin_amdgcn_s_barrier();
        __builtin_amdgcn_sched_barrier(0);
        readA(cur, 1);
        asm volatile("s_waitcnt lgkmcnt(0)" ::: "memory");
        __builtin_amdgcn_sched_barrier(0);
        __builtin_amdgcn_s_setprio(1); mfma16<1, 0>(acc, fa, fb); __builtin_amdgcn_s_setprio(0);
        // ---- phase 3 (q11): stage A'bot; no reads, no barrier needed ----
        stageA(cur ^ 1, nk0, 1);
        __builtin_amdgcn_s_setprio(1); mfma16<1, 1>(acc, fa, fb); __builtin_amdgcn_s_setprio(0);
        cur ^= 1;
    }
    // ---- tail tile (no prefetch; drain 4 -> 2 -> 0) ----
    asm volatile("s_waitcnt vmcnt(4)" ::: "memory");
    __builtin_amdgcn_s_barrier();
    __builtin_amdgcn_sched_barrier(0);
    readA(cur, 0); readB(cur, 0);
    asm volatile("s_waitcnt lgkmcnt(0)" ::: "memory");
    __builtin_amdgcn_sched_barrier(0);
    __builtin_amdgcn_s_setprio(1); mfma16<0, 0>(acc, fa, fb); __builtin_amdgcn_s_setprio(0);
    asm volatile("s_waitcnt vmcnt(2)" ::: "memory");
    __builtin_amdgcn_s_barrier();
    __builtin_amdgcn_sched_barrier(0);
    readB(cur, 1);
    asm volatile("s_waitcnt lgkmcnt(0)" ::: "memory");
    __builtin_amdgcn_sched_barrier(0);
    __builtin_amdgcn_s_setprio(1); mfma16<0, 1>(acc, fa, fb); __builtin_amdgcn_s_setprio(0);
    asm volatile("s_waitcnt vmcnt(0)" ::: "memory");
    __builtin_amdgcn_s_barrier();
    __builtin_amdgcn_sched_barrier(0);
    readA(cur, 1);
    asm volatile("s_waitcnt lgkmcnt(0)" ::: "memory");
    __builtin_amdgcn_sched_barrier(0);
    __builtin_amdgcn_s_setprio(1); mfma16<1, 0>(acc, fa, fb); __builtin_amdgcn_s_setprio(0);
    __builtin_amdgcn_s_setprio(1); mfma16<1, 1>(acc, fa, fb); __builtin_amdgcn_s_setprio(0);

    // ---- epilogue ----
    #pragma unroll
    for (int am = 0; am < 8; ++am) {
        #pragma unroll
        for (int j = 0; j < 4; ++j) {
            int m = bm + (wr << 7) + (am << 4) + ((lane >> 4) << 2) + j;
            #pragma unroll
            for (int an = 0; an < 4; ++an) {
                int n = bn + (wc << 6) + (an << 4) + (lane & 15);
                float v = acc[am][an][j] + bias[n];
                if constexpr (EPI == 0) {
                    ((__bf16*)Cout)[(size_t)m * N + n] = (__bf16)v;
                } else if constexpr (EPI == 1) {
                    int mg = m + r0;
                    int tr = win2tok(mg);
                    float g = mod[(mg >> 12) * 6144 + 2048 + n];
                    ((float*)Cout)[(size_t)tr * 1024 + n] = extra[(size_t)tr * 1024 + n] + g * v;
                } else if constexpr (EPI == 2) {
                    ((__bf16*)Cout)[(size_t)m * N + n] = (__bf16)gelu_tanh(v);
                } else {
                    int mg = m + r0;
                    float g = mod[(mg >> 12) * 6144 + 5120 + n];
                    ((float*)Cout)[(size_t)mg * 1024 + n] = extra[(size_t)mg * 1024 + n] + g * v;
                }
            }
        }
    }
}

// ---------------------------------------------------------------------------
// Rel-pos bias tables with LDS-staged bf16 rel matrices (31 rows x 64, rows
// padded to 72 elems = 144B, 16B-aligned). Wave reads are broadcast-heavy
// (2-4 distinct rows per wave). tab[((l>>8)*16+h)*256 + (l&255)][32].
// ---------------------------------------------------------------------------
__global__ __launch_bounds__(256)
void tab_k(const __bf16* __restrict__ qkv, const float* __restrict__ relh,
           const float* __restrict__ relw, __bf16* __restrict__ tab) {
    __shared__ __bf16 lR[2][31][72];
    for (int i = threadIdx.x; i < 1984; i += 256) {
        int row = i >> 6, c = i & 63;
        lR[0][row][c] = (__bf16)relh[i];
        lR[1][row][c] = (__bf16)relw[i];
    }
    __syncthreads();
    const int h = blockIdx.y;
    const int r = threadIdx.x >> 1, half = threadIdx.x & 1;
    const int l = blockIdx.x * 128 + r;
    const int lw = l & 255;
    const int qi = lw >> 4, qj = lw & 15;
    const __bf16* qrow = qkv + (size_t)l * 3072 + h * 64;
    float qq[64];
    #pragma unroll
    for (int c8 = 0; c8 < 8; ++c8) {
        bf16x8_t q8 = *(const bf16x8_t*)(qrow + (c8 << 3));
        #pragma unroll
        for (int e = 0; e < 8; ++e) qq[c8 * 8 + e] = (float)q8[e];
    }
    bf16x8_t oh, ow;
    #pragma unroll
    for (int kk = 0; kk < 8; ++kk) {
        int kg = (half << 3) + kk;
        const __bf16* Rh = &lR[0][qi - kg + 15][0];
        const __bf16* Rw = &lR[1][qj - kg + 15][0];
        float ah = 0.f, aw = 0.f;
        #pragma unroll
        for (int c8 = 0; c8 < 8; ++c8) {
            bf16x8_t r1 = *(const bf16x8_t*)(Rh + (c8 << 3));
            bf16x8_t r2 = *(const bf16x8_t*)(Rw + (c8 << 3));
            #pragma unroll
            for (int e = 0; e < 8; ++e) {
                ah += qq[c8 * 8 + e] * (float)r1[e];
                aw += qq[c8 * 8 + e] * (float)r2[e];
            }
        }
        oh[kk] = (__bf16)ah; ow[kk] = (__bf16)aw;
    }
    size_t idx = ((size_t)(l >> 8) * 16 + h) * 256 + lw;
    *(bf16x8_t*)(tab + idx * 32 + (half << 3))      = oh;
    *(bf16x8_t*)(tab + idx * 32 + 16 + (half << 3)) = ow;
}

// ---------------------------------------------------------------------------
// Window attention (unchanged from round 6, passing). Block = (window, head,
// q-half); 4 waves x 32 q-rows; K/V double-buffered; non-online softmax.
// ---------------------------------------------------------------------------
__global__ __launch_bounds__(256, 3)
void attn_k(const __bf16* __restrict__ qkv, const __bf16* __restrict__ tab,
            __bf16* __restrict__ out) {
    __shared__ __align__(16) __bf16 lP[4][32 * 32];
    __shared__ __align__(16) __bf16 lKt[2][64 * 64];
    __shared__ __align__(16) __bf16 lVt[2][64 * 64];
    __shared__ __align__(16) __bf16 lTab[128 * 32];

    const int blk = blockIdx.x;
    const int winc = blk >> 5, h = (blk >> 1) & 15, qh = blk & 1;
    const int tid = threadIdx.x, lane = tid & 63, wv = tid >> 6;
    const __bf16* base = qkv + (size_t)winc * 256 * 3072 + h * 64;
    const int q0 = qh << 7;

    {
        const __bf16* ts = tab + (((size_t)winc * 16 + h) * 256 + q0) * 32;
        #pragma unroll
        for (int q = 0; q < 2; ++q) {
            int c = (wv << 1) + q;
            gload_lds16(ts + c * 512 + lane * 8, lTab + c * 512);
        }
    }
    bf16x8_t qf[2][2];
    #pragma unroll
    for (int mi = 0; mi < 2; ++mi)
        #pragma unroll
        for (int ks = 0; ks < 2; ++ks) {
            int l = q0 + (wv << 5) + (mi << 4) + (lane & 15);
            qf[mi][ks] = *(const bf16x8_t*)(base + (size_t)l * 3072 + (((ks << 2) + (lane >> 4)) << 3));
        }
    {
        const __bf16* kb = base + 1024;
        #pragma unroll
        for (int q = 0; q < 2; ++q) {
            int c = (wv << 1) + q;
            int kl = (c << 3) + (lane >> 3);
            gload_lds16(kb + (size_t)kl * 3072 + (((lane & 7) ^ (lane >> 3)) << 3),
                        lKt[0] + c * 512);
        }
        const __bf16* vb = base + 2048;
        bf16x8_t a = *(const bf16x8_t*)(vb + (size_t)(tid >> 3) * 3072 + ((tid & 7) << 3));
        bf16x8_t b = *(const bf16x8_t*)(vb + (size_t)(32 + (tid >> 3)) * 3072 + ((tid & 7) << 3));
        int lc = tid & 7;
        #pragma unroll
        for (int e = 0; e < 8; ++e) {
            lVt[0][vt_addr(lc * 8 + e, tid >> 3)]        = a[e];
            lVt[0][vt_addr(lc * 8 + e, 32 + (tid >> 3))] = b[e];
        }
    }
    __syncthreads();

    float twv[2][4];
    #pragma unroll
    for (int mi = 0; mi < 2; ++mi)
        #pragma unroll
        for (int j = 0; j < 4; ++j) {
            int qr = (wv << 5) + (mi << 4) + ((lane >> 4) << 2) + j;
            twv[mi][j] = (float)lTab[qr * 32 + 16 + (lane & 15)];
        }

    const f32x4 z4 = {0.f, 0.f, 0.f, 0.f};
    f32x4 oacc[2][4];
    #pragma unroll
    for (int a = 0; a < 2; ++a)
        #pragma unroll
        for (int b = 0; b < 4; ++b) oacc[a][b] = z4;
    float rsum[2][4];
    #pragma unroll
    for (int a = 0; a < 2; ++a)
        #pragma unroll
        for (int j = 0; j < 4; ++j) rsum[a][j] = 0.f;
    __bf16* lPw = lP[wv];

    int cur = 0;
    for (int kt = 0; kt < 4; ++kt) {
        const bool pre = (kt < 3);
        bf16x8_t v8a, v8b;
        if (pre) {
            const __bf16* kb = base + 1024 + (size_t)(kt + 1) * 64 * 3072;
            #pragma unroll
            for (int q = 0; q < 2; ++q) {
                int c = (wv << 1) + q;
                int kl = (c << 3) + (lane >> 3);
                gload_lds16(kb + (size_t)kl * 3072 + (((lane & 7) ^ (lane >> 3)) << 3),
                            lKt[cur ^ 1] + c * 512);
            }
            const __bf16* vb = base + 2048 + (size_t)(kt + 1) * 64 * 3072;
            v8a = *(const bf16x8_t*)(vb + (size_t)(tid >> 3) * 3072 + ((tid & 7) << 3));
            v8b = *(const bf16x8_t*)(vb + (size_t)(32 + (tid >> 3)) * 3072 + ((tid & 7) << 3));
        }

        f32x4 s[2][4];
        #pragma unroll
        for (int a = 0; a < 2; ++a)
            #pragma unroll
            for (int b = 0; b < 4; ++b) s[a][b] = z4;
        #pragma unroll
        for (int ks = 0; ks < 2; ++ks) {
            bf16x8_t kf[4];
            #pragma unroll
            for (int ni = 0; ni < 4; ++ni)
                kf[ni] = lds_frag(lKt[cur], (ni << 4) + (lane & 15), (ks << 2) + (lane >> 4), 64);
            #pragma unroll
            for (int mi = 0; mi < 2; ++mi)
                #pragma unroll
                for (int ni = 0; ni < 4; ++ni)
                    s[mi][ni] = __builtin_amdgcn_mfma_f32_16x16x32_bf16(qf[mi][ks], kf[ni], s[mi][ni], 0, 0, 0);
        }

        #pragma unroll
        for (int mi = 0; mi < 2; ++mi) {
            #pragma unroll
            for (int j = 0; j < 4; ++j) {
                int qr = (wv << 5) + (mi << 4) + ((lane >> 4) << 2) + j;
                bf16x4_t th4 = *(const bf16x4_t*)(lTab + qr * 32 + (kt << 2));
                float rs = 0.f;
                #pragma unroll
                for (int ni = 0; ni < 4; ++ni) {
                    float p = __expf(s[mi][ni][j] * 0.125f + (float)th4[ni] + twv[mi][j]);
                    s[mi][ni][j] = p;
                    rs += p;
                }
                rsum[mi][j] += rs;
            }
        }

        #pragma unroll
        for (int hf = 0; hf < 2; ++hf) {
            #pragma unroll
            for (int mi = 0; mi < 2; ++mi) {
                #pragma unroll
                for (int j = 0; j < 4; ++j) {
                    int rl = (mi << 4) + ((lane >> 4) << 2) + j;
                    #pragma unroll
                    for (int b = 0; b < 2; ++b) {
                        int col = (b << 4) + (lane & 15);
                        lPw[rl * 32 + ((((col >> 3) ^ ((rl >> 1) & 3)) << 3) | (col & 7))] =
                            (__bf16)s[mi][(hf << 1) + b][j];
                    }
                }
            }
            bf16x8_t pf[2], vf[4];
            #pragma unroll
            for (int mi = 0; mi < 2; ++mi)
                pf[mi] = p_frag(lPw, (mi << 4) + (lane & 15), lane >> 4);
            #pragma unroll
            for (int no = 0; no < 4; ++no) {
                int d = (no << 4) + (lane & 15);
                vf[no] = *(const bf16x8_t*)(lVt[cur] + vt_addr(d, ((hf << 2) + (lane >> 4)) << 3));
            }
            #pragma unroll
            for (int mi = 0; mi < 2; ++mi)
                #pragma unroll
                for (int no = 0; no < 4; ++no)
                    oacc[mi][no] = __builtin_amdgcn_mfma_f32_16x16x32_bf16(pf[mi], vf[no], oacc[mi][no], 0, 0, 0);
        }

        if (pre) {
            int lc = tid & 7;
            #pragma unroll
            for (int e = 0; e < 8; ++e) {
                lVt[cur ^ 1][vt_addr(lc * 8 + e, tid >> 3)]        = v8a[e];
                lVt[cur ^ 1][vt_addr(lc * 8 + e, 32 + (tid >> 3))] = v8b[e];
            }
        }
        __syncthreads();
        cur ^= 1;
    }

    #pragma unroll
    for (int mi = 0; mi < 2; ++mi) {
        #pragma unroll
        for (int j = 0; j < 4; ++j) {
            float rs = rsum[mi][j];
            #pragma unroll
            for (int msk = 1; msk < 16; msk <<= 1) rs += __shfl_xor(rs, msk);
            float inv = 1.f / rs;
            int l = q0 + (wv << 5) + (mi << 4) + ((lane >> 4) << 2) + j;
            #pragma unroll
            for (int no = 0; no < 4; ++no) {
                int col = (no << 4) + (lane & 15);
                out[(size_t)(winc * 256 + l) * 1024 + h * 64 + col] = (__bf16)(oacc[mi][no][j] * inv);
            }
        }
    }
}

// ---------------------------------------------------------------------------
extern "C" void kernel_launch(void* const* d_in, const int* in_sizes, int n_in,
                              void* d_out, int out_size, void* d_ws, size_t ws_size,
                              hipStream_t stream) {
    const float* x      = (const float*)d_in[0];
    const float* c      = (const float*)d_in[1];
    const float* qkv_w  = (const float*)d_in[2];
    const float* qkv_b  = (const float*)d_in[3];
    const float* proj_w = (const float*)d_in[4];
    const float* proj_b = (const float*)d_in[5];
    const float* rel_h  = (const float*)d_in[6];
    const float* rel_w  = (const float*)d_in[7];
    const float* ada_w  = (const float*)d_in[8];
    const float* ada_b  = (const float*)d_in[9];
    const float* fc1_w  = (const float*)d_in[10];
    const float* fc1_b  = (const float*)d_in[11];
    const float* fc2_w  = (const float*)d_in[12];
    const float* fc2_b  = (const float*)d_in[13];
    float* xo = (float*)d_out;

    char* ws = (char*)d_ws;
    const size_t MB = 1ull << 20;
    int CH = 0;
    const int cands[7] = {16384, 8192, 4096, 2048, 1024, 512, 256};
    for (int i = 0; i < 7; ++i)
        if (26 * MB + (size_t)cands[i] * 10240 <= ws_size) { CH = cands[i]; break; }
    if (CH == 0) {
        zero_k<<<65536, 256, 0, stream>>>(xo, 16777216);
        return;
    }
    const int NCH = 16384 / CH;

    // enable 128KB dynamic LDS for the 8-phase GEMM (idempotent, host-side)
    const int LDSB = 131072;
    hipFuncSetAttribute((const void*)&gemm256<0>, hipFuncAttributeMaxDynamicSharedMemorySize, LDSB);
    hipFuncSetAttribute((const void*)&gemm256<1>, hipFuncAttributeMaxDynamicSharedMemorySize, LDSB);
    hipFuncSetAttribute((const void*)&gemm256<2>, hipFuncAttributeMaxDynamicSharedMemorySize, LDSB);
    hipFuncSetAttribute((const void*)&gemm256<3>, hipFuncAttributeMaxDynamicSharedMemorySize, LDSB);

    float*  ws_silu = (float*)(ws);
    float*  ws_mod  = (float*)(ws + 65536);
    __bf16* w_qkv   = (__bf16*)(ws + 1 * MB);
    __bf16* w_proj  = (__bf16*)(ws + 7 * MB);
    __bf16* w_fc1   = (__bf16*)(ws + 9 * MB);
    __bf16* w_fc2   = (__bf16*)(ws + 17 * MB);
    __bf16* bufA    = (__bf16*)(ws + 26 * MB);
    __bf16* bufB    = (__bf16*)(ws + 26 * MB + (size_t)CH * 2048);
    __bf16* tabbuf  = bufB + (size_t)CH * 3072;

    silu_k   <<<16,   256, 0, stream>>>(c, ws_silu, 4096);
    mod_gemv <<<6144, 256, 0, stream>>>(ws_silu, ada_w, ada_b, ws_mod);
    conv_bf16<<<3072, 256, 0, stream>>>(qkv_w,  w_qkv,  786432);
    conv_bf16<<<1024, 256, 0, stream>>>(proj_w, w_proj, 262144);
    conv_bf16<<<4096, 256, 0, stream>>>(fc1_w,  w_fc1,  1048576);
    conv_bf16<<<4096, 256, 0, stream>>>(fc2_w,  w_fc2,  1048576);

    for (int ci = 0; ci < NCH; ++ci) {
        int r0 = ci * CH;
        ln_mod_k<<<CH, 256, 0, stream>>>(x, ws_mod, 0, 1024, bufA, 1, r0);
        gemm256<0><<<dim3(12, CH / 256), 512, LDSB, stream>>>(bufA, w_qkv, qkv_b, bufB,
                                                              nullptr, nullptr, 3072, 1024, r0);
        tab_k<<<dim3(CH / 128, 16), 256, 0, stream>>>(bufB, rel_h, rel_w, tabbuf);
        attn_k<<<(CH / 256) * 32, 256, 0, stream>>>(bufB, tabbuf, bufA);
        gemm256<1><<<dim3(4, CH / 256), 512, LDSB, stream>>>(bufA, w_proj, proj_b, xo,
                                                             x, ws_mod, 1024, 1024, r0);
    }
    for (int ci = 0; ci < NCH; ++ci) {
        int r0 = ci * CH;
        ln_mod_k<<<CH, 256, 0, stream>>>(xo, ws_mod, 3072, 4096, bufA, 0, r0);
        gemm256<2><<<dim3(16, CH / 256), 512, LDSB, stream>>>(bufA, w_fc1, fc1_b, bufB,
                                                              nullptr, nullptr, 4096, 1024, r0);
        gemm256<3><<<dim3(4, CH / 256), 512, LDSB, stream>>>(bufB, w_fc2, fc2_b, xo,
                                                             xo, ws_mod, 1024, 4096, r0);
    }
}

// Round 8
// 641.445 us; speedup vs baseline: 1.3133x; 1.0048x over previous
//
#include <hip/hip_runtime.h>
#include <cstdint>
#include <cstddef>

// ---------------------------------------------------------------------------
// MultiStageDiT round 8: gemm256 re-scheduled to the verified 8-phase
// discipline: ds_reads issued BEFORE the phase barrier (latency hides under
// barrier arrival), vmcnt counted ONCE per K-tile at the boundary (6; final
// boundary 0), 2 barriers/phase, setprio MFMA clusters, bijective XCD swizzle.
// attn_k / tab_k / LN / prep unchanged from round 7 (passing, 644us).
// ---------------------------------------------------------------------------

typedef float  f32x4    __attribute__((ext_vector_type(4)));
typedef __bf16 bf16x8_t __attribute__((ext_vector_type(8)));
typedef __bf16 bf16x4_t __attribute__((ext_vector_type(4)));

#define DEV __device__ __forceinline__

DEV void gload_lds16(const void* g, void* l) {
    auto gp = (const uint32_t __attribute__((address_space(1)))*)(uintptr_t)g;
    auto lp = (uint32_t __attribute__((address_space(3)))*)(uint32_t)(uintptr_t)l;
    __builtin_amdgcn_global_load_lds(gp, lp, 16, 0, 0);
}

// row-major LDS tile, 16B chunks XOR-swizzled by (row&7)
DEV bf16x8_t lds_frag(const __bf16* base, int row, int chunk, int row_elems) {
    return *(const bf16x8_t*)(base + row * row_elems + ((chunk ^ (row & 7)) << 3));
}

// 32-elem-row P tile: XOR key (row>>1)&3
DEV bf16x8_t p_frag(const __bf16* base, int row, int chunk) {
    return *(const bf16x8_t*)(base + row * 32 + ((chunk ^ ((row >> 1) & 3)) << 3));
}

// V^T tile elem address: key (d&7)^((d>>3)&7)
DEV int vt_addr(int d, int k) {
    return d * 64 + ((((k >> 3) ^ (d & 7) ^ ((d >> 3) & 7)) << 3) | (k & 7));
}

DEV float gelu_tanh(float v) {
    float u = 0.7978845608028654f * (v + 0.044715f * v * v * v);
    float e = __expf(2.f * u);
    float th = 1.f - 2.f / (e + 1.f);
    return 0.5f * v * (1.f + th);
}

DEV int win2tok(int r) {
    int nb = r >> 12, wi = (r >> 8) & 15, l = r & 255;
    return (nb << 12) + (wi >> 2) * 1024 + (l >> 4) * 64 + (wi & 3) * 16 + (l & 15);
}

// ---------------------------------------------------------------------------
// prep kernels
// ---------------------------------------------------------------------------
__global__ void silu_k(const float* __restrict__ c, float* __restrict__ o, int n) {
    int i = blockIdx.x * 256 + threadIdx.x;
    if (i < n) { float v = c[i]; o[i] = v / (1.f + __expf(-v)); }
}

__global__ void zero_k(float* o, int n) {
    int i = blockIdx.x * 256 + threadIdx.x;
    if (i < n) o[i] = 0.f;
}

__global__ void conv_bf16(const float* __restrict__ s, __bf16* __restrict__ d, int n4) {
    int i = blockIdx.x * 256 + threadIdx.x;
    if (i < n4) {
        float4 v = ((const float4*)s)[i];
        bf16x4_t o; o[0] = (__bf16)v.x; o[1] = (__bf16)v.y; o[2] = (__bf16)v.z; o[3] = (__bf16)v.w;
        ((bf16x4_t*)d)[i] = o;
    }
}

__global__ __launch_bounds__(256)
void mod_gemv(const float* __restrict__ sc, const float* __restrict__ w,
              const float* __restrict__ b, float* __restrict__ mod) {
    int o = (blockIdx.x << 2) + (threadIdx.x >> 6);
    int lane = threadIdx.x & 63;
    int n = o / 6144, col = o % 6144;
    const float4* wr = (const float4*)(w + (size_t)col * 1024);
    const float4* sr = (const float4*)(sc + n * 1024);
    float acc = 0.f;
    #pragma unroll 4
    for (int i = lane; i < 256; i += 64) {
        float4 a = wr[i], x = sr[i];
        acc += a.x * x.x + a.y * x.y + a.z * x.z + a.w * x.w;
    }
    #pragma unroll
    for (int m = 1; m < 64; m <<= 1) acc += __shfl_xor(acc, m);
    if (lane == 0) mod[o] = acc + b[col];
}

__global__ __launch_bounds__(256)
void ln_mod_k(const float* __restrict__ src, const float* __restrict__ mod,
              int sh_off, int sc_off, __bf16* __restrict__ out, int permute, int r0) {
    int rl = blockIdx.x;
    int r = rl + r0;
    int nb = r >> 12;
    int t = permute ? win2tok(r) : r;
    float4 v = ((const float4*)(src + (size_t)t * 1024))[threadIdx.x];
    float s  = v.x + v.y + v.z + v.w;
    float sq = v.x * v.x + v.y * v.y + v.z * v.z + v.w * v.w;
    #pragma unroll
    for (int m = 1; m < 64; m <<= 1) { s += __shfl_xor(s, m); sq += __shfl_xor(sq, m); }
    __shared__ float ps[4], pq[4];
    int wv = threadIdx.x >> 6, ln = threadIdx.x & 63;
    if (ln == 0) { ps[wv] = s; pq[wv] = sq; }
    __syncthreads();
    s  = ps[0] + ps[1] + ps[2] + ps[3];
    sq = pq[0] + pq[1] + pq[2] + pq[3];
    float mean = s * (1.f / 1024.f);
    float var  = sq * (1.f / 1024.f) - mean * mean;
    float rstd = rsqrtf(var + 1e-6f);
    int c = threadIdx.x << 2;
    const float* mrow = mod + nb * 6144;
    float4 scv = *(const float4*)(mrow + sc_off + c);
    float4 shv = *(const float4*)(mrow + sh_off + c);
    bf16x4_t o;
    o[0] = (__bf16)((v.x - mean) * rstd * (1.f + scv.x) + shv.x);
    o[1] = (__bf16)((v.y - mean) * rstd * (1.f + scv.y) + shv.y);
    o[2] = (__bf16)((v.z - mean) * rstd * (1.f + scv.z) + shv.z);
    o[3] = (__bf16)((v.w - mean) * rstd * (1.f + scv.w) + shv.w);
    *(bf16x4_t*)(out + (size_t)rl * 1024 + c) = o;
}

// ---------------------------------------------------------------------------
// 256x256 8-phase bf16 GEMM, template-faithful schedule.
// 512 threads = 8 waves (2M x 4N); per-wave C 128x64; BK=64; LDS 128KB dbuf.
// Half-stream order per tile: [A0, B0, B1, A1]; stage half (p+7) at phase p.
// Quadrant reads: ph0 A0+B0 (12 ds_read), ph1 B1 (4), ph2 A1 (8), ph3 none.
// vmcnt(6) ONCE per tile at ph3 (boundary); vmcnt(0) at the final boundary.
// Per phase: reads, stage, [vmcnt], s_barrier, lgkmcnt(0)+sched_barrier,
// setprio(1) 16 MFMA setprio(0), s_barrier.
// ---------------------------------------------------------------------------
template <int PM, int PN>
DEV void mfma16(f32x4 (&acc)[8][4], bf16x8_t (&fa)[4][2], bf16x8_t (&fb)[2][2][2]) {
    #pragma unroll
    for (int ks = 0; ks < 2; ++ks)
        #pragma unroll
        for (int mi = 0; mi < 4; ++mi)
            #pragma unroll
            for (int nn = 0; nn < 2; ++nn)
                acc[PM * 4 + mi][PN * 2 + nn] = __builtin_amdgcn_mfma_f32_16x16x32_bf16(
                    fa[mi][ks], fb[PN][nn][ks], acc[PM * 4 + mi][PN * 2 + nn], 0, 0, 0);
}

#define GBAR  __builtin_amdgcn_s_barrier()
#define LGKM0 do { asm volatile("s_waitcnt lgkmcnt(0)" ::: "memory"); \
                   __builtin_amdgcn_sched_barrier(0); } while (0)
#define PRIO1 __builtin_amdgcn_s_setprio(1)
#define PRIO0 __builtin_amdgcn_s_setprio(0)

template <int EPI>
__global__ __launch_bounds__(512)
void gemm256(const __bf16* __restrict__ A, const __bf16* __restrict__ B,
             const float* __restrict__ bias, void* __restrict__ Cout,
             const float* __restrict__ extra, const float* __restrict__ mod,
             int N, int K, int r0, int gx) {
    extern __shared__ __align__(16) char smem[];
    __bf16* lA = (__bf16*)smem;             // [2][256*64]
    __bf16* lB = lA + 2 * 16384;            // [2][256*64]
    const int tid = threadIdx.x, lane = tid & 63, wv = tid >> 6;
    const int wr = wv >> 2, wc = wv & 3;

    // bijective XCD-aware block swizzle (1-D grid)
    const int nwg = gridDim.x;
    const int qq = nwg >> 3, rr = nwg & 7;
    const int xcd = blockIdx.x & 7, pos = blockIdx.x >> 3;
    const int nid = (xcd < rr ? xcd * (qq + 1) : rr * (qq + 1) + (xcd - rr) * qq) + pos;
    const int bm = (nid / gx) << 8, bn = (nid % gx) << 8;

    f32x4 acc[8][4];
    const f32x4 z4 = {0.f, 0.f, 0.f, 0.f};
    #pragma unroll
    for (int i = 0; i < 8; ++i)
        #pragma unroll
        for (int j = 0; j < 4; ++j) acc[i][j] = z4;

    bf16x8_t fa[4][2], fb[2][2][2];
    const int gc8 = (((lane & 7) ^ (lane >> 3)) << 3);   // pre-swizzled src chunk

    auto stageA = [&](int buf, int k0, int h) {
        #pragma unroll
        for (int j = 0; j < 2; ++j) {
            int rb = (h << 6) + (j << 7) + (wv << 3);
            gload_lds16(A + (size_t)(bm + rb + (lane >> 3)) * K + k0 + gc8,
                        lA + buf * 16384 + rb * 64);
        }
    };
    auto stageB = [&](int buf, int k0, int h) {
        #pragma unroll
        for (int j = 0; j < 2; ++j) {
            int rb = (h << 5) + (j << 7) + ((wv & 3) << 3) + ((wv >> 2) << 6);
            gload_lds16(B + (size_t)(bn + rb + (lane >> 3)) * K + k0 + gc8,
                        lB + buf * 16384 + rb * 64);
        }
    };
    auto readA = [&](int buf, int pm) {
        #pragma unroll
        for (int mi = 0; mi < 4; ++mi)
            #pragma unroll
            for (int ks = 0; ks < 2; ++ks)
                fa[mi][ks] = lds_frag(lA + buf * 16384,
                                      (wr << 7) + (pm << 6) + (mi << 4) + (lane & 15),
                                      (ks << 2) + (lane >> 4), 64);
    };
    auto readB = [&](int buf, int pn) {
        #pragma unroll
        for (int ni = 0; ni < 2; ++ni)
            #pragma unroll
            for (int ks = 0; ks < 2; ++ks)
                fb[pn][ni][ks] = lds_frag(lB + buf * 16384,
                                          (wc << 6) + (pn << 5) + (ni << 4) + (lane & 15),
                                          (ks << 2) + (lane >> 4), 64);
    };

    const int nt = K >> 6;
    // prologue: stage halves 0..6 (tile0 full + tile1 A0,B0,B1); certify tile0
    stageA(0, 0, 0); stageB(0, 0, 0); stageB(0, 0, 1); stageA(0, 0, 1);
    stageA(1, 64, 0); stageB(1, 64, 0); stageB(1, 64, 1);
    asm volatile("s_waitcnt vmcnt(6)" ::: "memory");
    GBAR;

    int cur = 0;
    for (int t = 0; t < nt - 1; ++t) {
        const int k2 = (t + 2) << 6;
        const bool s2 = (t + 2 < nt);
        // ---- phase 0: read A0,B0(cur); stage A1 of t+1 (buf^1) ----
        readA(cur, 0); readB(cur, 0);
        stageA(cur ^ 1, (t + 1) << 6, 1);
        GBAR; LGKM0;
        PRIO1; mfma16<0, 0>(acc, fa, fb); PRIO0;
        GBAR;
        // ---- phase 1: read B1(cur); stage A0 of t+2 (cur) ----
        readB(cur, 1);
        if (s2) stageA(cur, k2, 0);
        GBAR; LGKM0;
        PRIO1; mfma16<0, 1>(acc, fa, fb); PRIO0;
        GBAR;
        // ---- phase 2: read A1(cur); stage B0 of t+2 (cur) ----
        readA(cur, 1);
        if (s2) stageB(cur, k2, 0);
        GBAR; LGKM0;
        PRIO1; mfma16<1, 0>(acc, fa, fb); PRIO0;
        GBAR;
        // ---- phase 3: stage B1 of t+2 (cur); boundary vmcnt; no reads ----
        if (s2) stageB(cur, k2, 1);
        if (t == nt - 2) asm volatile("s_waitcnt vmcnt(0)" ::: "memory");
        else             asm volatile("s_waitcnt vmcnt(6)" ::: "memory");
        GBAR;
        PRIO1; mfma16<1, 1>(acc, fa, fb); PRIO0;
        GBAR;
        cur ^= 1;
    }
    // ---- tail tile (all data certified by final boundary vmcnt(0)) ----
    readA(cur, 0); readB(cur, 0); readB(cur, 1);
    LGKM0;
    PRIO1; mfma16<0, 0>(acc, fa, fb); mfma16<0, 1>(acc, fa, fb); PRIO0;
    readA(cur, 1);
    LGKM0;
    PRIO1; mfma16<1, 0>(acc, fa, fb); mfma16<1, 1>(acc, fa, fb); PRIO0;

    // ---- epilogue ----
    #pragma unroll
    for (int am = 0; am < 8; ++am) {
        #pragma unroll
        for (int j = 0; j < 4; ++j) {
            int m = bm + (wr << 7) + (am << 4) + ((lane >> 4) << 2) + j;
            #pragma unroll
            for (int an = 0; an < 4; ++an) {
                int n = bn + (wc << 6) + (an << 4) + (lane & 15);
                float v = acc[am][an][j] + bias[n];
                if constexpr (EPI == 0) {
                    ((__bf16*)Cout)[(size_t)m * N + n] = (__bf16)v;
                } else if constexpr (EPI == 1) {
                    int mg = m + r0;
                    int tr = win2tok(mg);
                    float g = mod[(mg >> 12) * 6144 + 2048 + n];
                    ((float*)Cout)[(size_t)tr * 1024 + n] = extra[(size_t)tr * 1024 + n] + g * v;
                } else if constexpr (EPI == 2) {
                    ((__bf16*)Cout)[(size_t)m * N + n] = (__bf16)gelu_tanh(v);
                } else {
                    int mg = m + r0;
                    float g = mod[(mg >> 12) * 6144 + 5120 + n];
                    ((float*)Cout)[(size_t)mg * 1024 + n] = extra[(size_t)mg * 1024 + n] + g * v;
                }
            }
        }
    }
}

// ---------------------------------------------------------------------------
// Rel-pos bias tables (LDS-staged rel matrices) — unchanged from round 7.
// ---------------------------------------------------------------------------
__global__ __launch_bounds__(256)
void tab_k(const __bf16* __restrict__ qkv, const float* __restrict__ relh,
           const float* __restrict__ relw, __bf16* __restrict__ tab) {
    __shared__ __bf16 lR[2][31][72];
    for (int i = threadIdx.x; i < 1984; i += 256) {
        int row = i >> 6, c = i & 63;
        lR[0][row][c] = (__bf16)relh[i];
        lR[1][row][c] = (__bf16)relw[i];
    }
    __syncthreads();
    const int h = blockIdx.y;
    const int r = threadIdx.x >> 1, half = threadIdx.x & 1;
    const int l = blockIdx.x * 128 + r;
    const int lw = l & 255;
    const int qi = lw >> 4, qj = lw & 15;
    const __bf16* qrow = qkv + (size_t)l * 3072 + h * 64;
    float qq[64];
    #pragma unroll
    for (int c8 = 0; c8 < 8; ++c8) {
        bf16x8_t q8 = *(const bf16x8_t*)(qrow + (c8 << 3));
        #pragma unroll
        for (int e = 0; e < 8; ++e) qq[c8 * 8 + e] = (float)q8[e];
    }
    bf16x8_t oh, ow;
    #pragma unroll
    for (int kk = 0; kk < 8; ++kk) {
        int kg = (half << 3) + kk;
        const __bf16* Rh = &lR[0][qi - kg + 15][0];
        const __bf16* Rw = &lR[1][qj - kg + 15][0];
        float ah = 0.f, aw = 0.f;
        #pragma unroll
        for (int c8 = 0; c8 < 8; ++c8) {
            bf16x8_t r1 = *(const bf16x8_t*)(Rh + (c8 << 3));
            bf16x8_t r2 = *(const bf16x8_t*)(Rw + (c8 << 3));
            #pragma unroll
            for (int e = 0; e < 8; ++e) {
                ah += qq[c8 * 8 + e] * (float)r1[e];
                aw += qq[c8 * 8 + e] * (float)r2[e];
            }
        }
        oh[kk] = (__bf16)ah; ow[kk] = (__bf16)aw;
    }
    size_t idx = ((size_t)(l >> 8) * 16 + h) * 256 + lw;
    *(bf16x8_t*)(tab + idx * 32 + (half << 3))      = oh;
    *(bf16x8_t*)(tab + idx * 32 + 16 + (half << 3)) = ow;
}

// ---------------------------------------------------------------------------
// Window attention — unchanged from round 6/7 (passing).
// ---------------------------------------------------------------------------
__global__ __launch_bounds__(256, 3)
void attn_k(const __bf16* __restrict__ qkv, const __bf16* __restrict__ tab,
            __bf16* __restrict__ out) {
    __shared__ __align__(16) __bf16 lP[4][32 * 32];
    __shared__ __align__(16) __bf16 lKt[2][64 * 64];
    __shared__ __align__(16) __bf16 lVt[2][64 * 64];
    __shared__ __align__(16) __bf16 lTab[128 * 32];

    const int blk = blockIdx.x;
    const int winc = blk >> 5, h = (blk >> 1) & 15, qh = blk & 1;
    const int tid = threadIdx.x, lane = tid & 63, wv = tid >> 6;
    const __bf16* base = qkv + (size_t)winc * 256 * 3072 + h * 64;
    const int q0 = qh << 7;

    {
        const __bf16* ts = tab + (((size_t)winc * 16 + h) * 256 + q0) * 32;
        #pragma unroll
        for (int q = 0; q < 2; ++q) {
            int c = (wv << 1) + q;
            gload_lds16(ts + c * 512 + lane * 8, lTab + c * 512);
        }
    }
    bf16x8_t qf[2][2];
    #pragma unroll
    for (int mi = 0; mi < 2; ++mi)
        #pragma unroll
        for (int ks = 0; ks < 2; ++ks) {
            int l = q0 + (wv << 5) + (mi << 4) + (lane & 15);
            qf[mi][ks] = *(const bf16x8_t*)(base + (size_t)l * 3072 + (((ks << 2) + (lane >> 4)) << 3));
        }
    {
        const __bf16* kb = base + 1024;
        #pragma unroll
        for (int q = 0; q < 2; ++q) {
            int c = (wv << 1) + q;
            int kl = (c << 3) + (lane >> 3);
            gload_lds16(kb + (size_t)kl * 3072 + (((lane & 7) ^ (lane >> 3)) << 3),
                        lKt[0] + c * 512);
        }
        const __bf16* vb = base + 2048;
        bf16x8_t a = *(const bf16x8_t*)(vb + (size_t)(tid >> 3) * 3072 + ((tid & 7) << 3));
        bf16x8_t b = *(const bf16x8_t*)(vb + (size_t)(32 + (tid >> 3)) * 3072 + ((tid & 7) << 3));
        int lc = tid & 7;
        #pragma unroll
        for (int e = 0; e < 8; ++e) {
            lVt[0][vt_addr(lc * 8 + e, tid >> 3)]        = a[e];
            lVt[0][vt_addr(lc * 8 + e, 32 + (tid >> 3))] = b[e];
        }
    }
    __syncthreads();

    float twv[2][4];
    #pragma unroll
    for (int mi = 0; mi < 2; ++mi)
        #pragma unroll
        for (int j = 0; j < 4; ++j) {
            int qr = (wv << 5) + (mi << 4) + ((lane >> 4) << 2) + j;
            twv[mi][j] = (float)lTab[qr * 32 + 16 + (lane & 15)];
        }

    const f32x4 z4 = {0.f, 0.f, 0.f, 0.f};
    f32x4 oacc[2][4];
    #pragma unroll
    for (int a = 0; a < 2; ++a)
        #pragma unroll
        for (int b = 0; b < 4; ++b) oacc[a][b] = z4;
    float rsum[2][4];
    #pragma unroll
    for (int a = 0; a < 2; ++a)
        #pragma unroll
        for (int j = 0; j < 4; ++j) rsum[a][j] = 0.f;
    __bf16* lPw = lP[wv];

    int cur = 0;
    for (int kt = 0; kt < 4; ++kt) {
        const bool pre = (kt < 3);
        bf16x8_t v8a, v8b;
        if (pre) {
            const __bf16* kb = base + 1024 + (size_t)(kt + 1) * 64 * 3072;
            #pragma unroll
            for (int q = 0; q < 2; ++q) {
                int c = (wv << 1) + q;
                int kl = (c << 3) + (lane >> 3);
                gload_lds16(kb + (size_t)kl * 3072 + (((lane & 7) ^ (lane >> 3)) << 3),
                            lKt[cur ^ 1] + c * 512);
            }
            const __bf16* vb = base + 2048 + (size_t)(kt + 1) * 64 * 3072;
            v8a = *(const bf16x8_t*)(vb + (size_t)(tid >> 3) * 3072 + ((tid & 7) << 3));
            v8b = *(const bf16x8_t*)(vb + (size_t)(32 + (tid >> 3)) * 3072 + ((tid & 7) << 3));
        }

        f32x4 s[2][4];
        #pragma unroll
        for (int a = 0; a < 2; ++a)
            #pragma unroll
            for (int b = 0; b < 4; ++b) s[a][b] = z4;
        #pragma unroll
        for (int ks = 0; ks < 2; ++ks) {
            bf16x8_t kf[4];
            #pragma unroll
            for (int ni = 0; ni < 4; ++ni)
                kf[ni] = lds_frag(lKt[cur], (ni << 4) + (lane & 15), (ks << 2) + (lane >> 4), 64);
            #pragma unroll
            for (int mi = 0; mi < 2; ++mi)
                #pragma unroll
                for (int ni = 0; ni < 4; ++ni)
                    s[mi][ni] = __builtin_amdgcn_mfma_f32_16x16x32_bf16(qf[mi][ks], kf[ni], s[mi][ni], 0, 0, 0);
        }

        #pragma unroll
        for (int mi = 0; mi < 2; ++mi) {
            #pragma unroll
            for (int j = 0; j < 4; ++j) {
                int qr = (wv << 5) + (mi << 4) + ((lane >> 4) << 2) + j;
                bf16x4_t th4 = *(const bf16x4_t*)(lTab + qr * 32 + (kt << 2));
                float rs = 0.f;
                #pragma unroll
                for (int ni = 0; ni < 4; ++ni) {
                    float p = __expf(s[mi][ni][j] * 0.125f + (float)th4[ni] + twv[mi][j]);
                    s[mi][ni][j] = p;
                    rs += p;
                }
                rsum[mi][j] += rs;
            }
        }

        #pragma unroll
        for (int hf = 0; hf < 2; ++hf) {
            #pragma unroll
            for (int mi = 0; mi < 2; ++mi) {
                #pragma unroll
                for (int j = 0; j < 4; ++j) {
                    int rl = (mi << 4) + ((lane >> 4) << 2) + j;
                    #pragma unroll
                    for (int b = 0; b < 2; ++b) {
                        int col = (b << 4) + (lane & 15);
                        lPw[rl * 32 + ((((col >> 3) ^ ((rl >> 1) & 3)) << 3) | (col & 7))] =
                            (__bf16)s[mi][(hf << 1) + b][j];
                    }
                }
            }
            bf16x8_t pf[2], vf[4];
            #pragma unroll
            for (int mi = 0; mi < 2; ++mi)
                pf[mi] = p_frag(lPw, (mi << 4) + (lane & 15), lane >> 4);
            #pragma unroll
            for (int no = 0; no < 4; ++no) {
                int d = (no << 4) + (lane & 15);
                vf[no] = *(const bf16x8_t*)(lVt[cur] + vt_addr(d, ((hf << 2) + (lane >> 4)) << 3));
            }
            #pragma unroll
            for (int mi = 0; mi < 2; ++mi)
                #pragma unroll
                for (int no = 0; no < 4; ++no)
                    oacc[mi][no] = __builtin_amdgcn_mfma_f32_16x16x32_bf16(pf[mi], vf[no], oacc[mi][no], 0, 0, 0);
        }

        if (pre) {
            int lc = tid & 7;
            #pragma unroll
            for (int e = 0; e < 8; ++e) {
                lVt[cur ^ 1][vt_addr(lc * 8 + e, tid >> 3)]        = v8a[e];
                lVt[cur ^ 1][vt_addr(lc * 8 + e, 32 + (tid >> 3))] = v8b[e];
            }
        }
        __syncthreads();
        cur ^= 1;
    }

    #pragma unroll
    for (int mi = 0; mi < 2; ++mi) {
        #pragma unroll
        for (int j = 0; j < 4; ++j) {
            float rs = rsum[mi][j];
            #pragma unroll
            for (int msk = 1; msk < 16; msk <<= 1) rs += __shfl_xor(rs, msk);
            float inv = 1.f / rs;
            int l = q0 + (wv << 5) + (mi << 4) + ((lane >> 4) << 2) + j;
            #pragma unroll
            for (int no = 0; no < 4; ++no) {
                int col = (no << 4) + (lane & 15);
                out[(size_t)(winc * 256 + l) * 1024 + h * 64 + col] = (__bf16)(oacc[mi][no][j] * inv);
            }
        }
    }
}

// ---------------------------------------------------------------------------
extern "C" void kernel_launch(void* const* d_in, const int* in_sizes, int n_in,
                              void* d_out, int out_size, void* d_ws, size_t ws_size,
                              hipStream_t stream) {
    const float* x      = (const float*)d_in[0];
    const float* c      = (const float*)d_in[1];
    const float* qkv_w  = (const float*)d_in[2];
    const float* qkv_b  = (const float*)d_in[3];
    const float* proj_w = (const float*)d_in[4];
    const float* proj_b = (const float*)d_in[5];
    const float* rel_h  = (const float*)d_in[6];
    const float* rel_w  = (const float*)d_in[7];
    const float* ada_w  = (const float*)d_in[8];
    const float* ada_b  = (const float*)d_in[9];
    const float* fc1_w  = (const float*)d_in[10];
    const float* fc1_b  = (const float*)d_in[11];
    const float* fc2_w  = (const float*)d_in[12];
    const float* fc2_b  = (const float*)d_in[13];
    float* xo = (float*)d_out;

    char* ws = (char*)d_ws;
    const size_t MB = 1ull << 20;
    int CH = 0;
    const int cands[7] = {16384, 8192, 4096, 2048, 1024, 512, 256};
    for (int i = 0; i < 7; ++i)
        if (26 * MB + (size_t)cands[i] * 10240 <= ws_size) { CH = cands[i]; break; }
    if (CH == 0) {
        zero_k<<<65536, 256, 0, stream>>>(xo, 16777216);
        return;
    }

    const int LDSB = 131072;
    hipFuncSetAttribute((const void*)&gemm256<0>, hipFuncAttributeMaxDynamicSharedMemorySize, LDSB);
    hipFuncSetAttribute((const void*)&gemm256<1>, hipFuncAttributeMaxDynamicSharedMemorySize, LDSB);
    hipFuncSetAttribute((const void*)&gemm256<2>, hipFuncAttributeMaxDynamicSharedMemorySize, LDSB);
    hipFuncSetAttribute((const void*)&gemm256<3>, hipFuncAttributeMaxDynamicSharedMemorySize, LDSB);

    const int NCH = 16384 / CH;
    float*  ws_silu = (float*)(ws);
    float*  ws_mod  = (float*)(ws + 65536);
    __bf16* w_qkv   = (__bf16*)(ws + 1 * MB);
    __bf16* w_proj  = (__bf16*)(ws + 7 * MB);
    __bf16* w_fc1   = (__bf16*)(ws + 9 * MB);
    __bf16* w_fc2   = (__bf16*)(ws + 17 * MB);
    __bf16* bufA    = (__bf16*)(ws + 26 * MB);
    __bf16* bufB    = (__bf16*)(ws + 26 * MB + (size_t)CH * 2048);
    __bf16* tabbuf  = bufB + (size_t)CH * 3072;

    silu_k   <<<16,   256, 0, stream>>>(c, ws_silu, 4096);
    mod_gemv <<<6144, 256, 0, stream>>>(ws_silu, ada_w, ada_b, ws_mod);
    conv_bf16<<<3072, 256, 0, stream>>>(qkv_w,  w_qkv,  786432);
    conv_bf16<<<1024, 256, 0, stream>>>(proj_w, w_proj, 262144);
    conv_bf16<<<4096, 256, 0, stream>>>(fc1_w,  w_fc1,  1048576);
    conv_bf16<<<4096, 256, 0, stream>>>(fc2_w,  w_fc2,  1048576);

    const int gy = CH / 256;
    for (int ci = 0; ci < NCH; ++ci) {
        int r0 = ci * CH;
        ln_mod_k<<<CH, 256, 0, stream>>>(x, ws_mod, 0, 1024, bufA, 1, r0);
        gemm256<0><<<12 * gy, 512, LDSB, stream>>>(bufA, w_qkv, qkv_b, bufB,
                                                   nullptr, nullptr, 3072, 1024, r0, 12);
        tab_k<<<dim3(CH / 128, 16), 256, 0, stream>>>(bufB, rel_h, rel_w, tabbuf);
        attn_k<<<(CH / 256) * 32, 256, 0, stream>>>(bufB, tabbuf, bufA);
        gemm256<1><<<4 * gy, 512, LDSB, stream>>>(bufA, w_proj, proj_b, xo,
                                                  x, ws_mod, 1024, 1024, r0, 4);
    }
    for (int ci = 0; ci < NCH; ++ci) {
        int r0 = ci * CH;
        ln_mod_k<<<CH, 256, 0, stream>>>(xo, ws_mod, 3072, 4096, bufA, 0, r0);
        gemm256<2><<<16 * gy, 512, LDSB, stream>>>(bufA, w_fc1, fc1_b, bufB,
                                                   nullptr, nullptr, 4096, 1024, r0, 16);
        gemm256<3><<<4 * gy, 512, LDSB, stream>>>(bufB, w_fc2, fc2_b, xo,
                                                  xo, ws_mod, 1024, 4096, r0, 4);
    }
}